// Round 7
// baseline (355.082 us; speedup 1.0000x reference)
//
#include <hip/hip_runtime.h>
#include <math.h>

#define DIMC  768
#define HEADS 12
#define NTOK  577
#define NPAT  576
#define NRELS 2209
#define BATCH 32
#define HDIM  64
#define MROWS (BATCH * NTOK)   // 18464
#define NQB   5                // q-blocks of 128 (640 padded rows)
#define NCH   10               // kv chunks of 64 (640 padded cols)

#define AS1 __attribute__((address_space(1)))
#define AS3 __attribute__((address_space(3)))

typedef __attribute__((ext_vector_type(8))) short bf16x8;
typedef __attribute__((ext_vector_type(4))) float f32x4;
typedef __attribute__((ext_vector_type(8))) unsigned short u16x8;

__device__ __forceinline__ unsigned short f2bf(float f) {
    unsigned int u = __float_as_uint(f);
    return (unsigned short)((u + 0x7FFFu + ((u >> 16) & 1u)) >> 16);
}
__device__ __forceinline__ float bf2f(unsigned short h) {
    return __uint_as_float(((unsigned int)h) << 16);
}

// ---------------------------------------------------------------------------
// fp32 -> bf16 convert
// ---------------------------------------------------------------------------
__global__ __launch_bounds__(256)
void f32_to_bf16_kernel(const float* __restrict__ in, unsigned short* __restrict__ out, int n4) {
    for (int i = blockIdx.x * 256 + threadIdx.x; i < n4; i += gridDim.x * 256) {
        float4 v = reinterpret_cast<const float4*>(in)[i];
        ushort4 r;
        r.x = f2bf(v.x); r.y = f2bf(v.y); r.z = f2bf(v.z); r.w = f2bf(v.w);
        reinterpret_cast<ushort4*>(out)[i] = r;
    }
}

// ---------------------------------------------------------------------------
// Bias panel in MFMA-fragment order (unchanged)
// ---------------------------------------------------------------------------
__global__ __launch_bounds__(256)
void build_biasF_kernel(const float* __restrict__ beta1,
                        const float* __restrict__ beta2,
                        const float* __restrict__ beta3,
                        unsigned short* __restrict__ biasF) {
    int idx = blockIdx.x * 256 + threadIdx.x;
    const int total = HEADS * NQB * NCH * 4 * 64 * 32;
    if (idx >= total) return;
    int r    = idx & 3;
    int bb   = (idx >> 2) & 3;
    int qi   = (idx >> 4) & 1;
    int lane = (idx >> 5) & 63;
    int wv   = (idx >> 11) & 3;
    int u    = idx >> 13;
    int c    = u % NCH;
    int i0b  = (u / NCH) % NQB;
    int h    = u / (NCH * NQB);
    int q = i0b * 128 + wv * 32 + qi * 16 + (lane & 15);
    int j = c * 64 + bb * 16 + ((lane >> 4) << 2) + r;
    float v;
    if (q >= NTOK || j >= NTOK) {
        v = -1e30f;
    } else if (q == NPAT) {
        v = beta1[h * NTOK + j];
    } else if (j == 0) {
        v = beta2[h * NPAT + q];
    } else {
        int p   = j - 1;
        int qi_ = q / 24, qj = q - qi_ * 24;
        int ri  = p / 24, ci = p - ri * 24;
        v = beta3[h * NRELS + (ri - qi_ + 23) * 47 + (ci - qj + 23)];
    }
    biasF[idx] = f2bf(v);
}

// ---------------------------------------------------------------------------
// V transpose (unchanged)
// ---------------------------------------------------------------------------
__global__ __launch_bounds__(256)
void vt_build_kernel(const unsigned short* __restrict__ qkv,
                     unsigned short* __restrict__ vtg) {
    __shared__ unsigned short T[64][72];
    const int c = blockIdx.x, h = blockIdx.y, b = blockIdx.z;
    const int tid = threadIdx.x;
    {
        int tok   = tid >> 2;
        int dq    = (tid & 3) << 4;
        int token = min(c * 64 + tok, NTOK - 1);
        const unsigned short* src = qkv + (size_t)(b * NTOK + token) * 2304 + 2 * DIMC + h * HDIM + dq;
        u16x8 a0 = *(const u16x8*)src;
        u16x8 a1 = *(const u16x8*)(src + 8);
        #pragma unroll
        for (int e = 0; e < 8; ++e) {
            T[dq + e][tok]     = (unsigned short)a0[e];
            T[dq + 8 + e][tok] = (unsigned short)a1[e];
        }
    }
    __syncthreads();
    {
        int d  = tid >> 2;
        int tq = (tid & 3) << 4;
        u16x8 r0 = *(const u16x8*)&T[d][tq];
        u16x8 r1 = *(const u16x8*)&T[d][tq + 8];
        unsigned short* dst = vtg + ((size_t)((b * HEADS + h) * HDIM) + d) * 640 + c * 64 + tq;
        *(u16x8*)dst       = r0;
        *(u16x8*)(dst + 8) = r1;
    }
}

// ---------------------------------------------------------------------------
// 128x128x(K) bf16 MFMA GEMM — counted-vmcnt double-buffer, 2 blocks/CU.
// 256 thr = 4 waves (2M x 2N), per-wave 64x64 = acc[4][4].
// LDS 64 KB: As[2][128x64] + Bs[2][128x64] -> 2 blocks/CU (cross-block
// latency hiding replaces deep per-block pipelining; m114 co-scheduling).
// T2 XOR swizzle via pre-swizzled global source + swizzled ds_read.
// Loop (R5-verified race-free): RD 16 frags -> lgkm0 -> barrier ->
// STAGE(t+2, freed buf) -> 32 MFMA (setprio) -> vmcnt(8) -> barrier.
// 8 global_load_lds per tile => vmcnt(8) = next tile landed, tile t+2 in
// flight across the barrier (never drains to 0 mid-loop).
// Requires N%128==0, K%128==0. M ragged (reads clamped, writes guarded).
// ---------------------------------------------------------------------------
template<bool ADD_BIAS, bool OUT_BF16, bool SCALE_Q>
__global__ __launch_bounds__(256, 2)
void gemm_128(const unsigned short* __restrict__ A,
              const unsigned short* __restrict__ B,
              const float* __restrict__ bias,
              void* __restrict__ Cv,
              int M, int N, int K, int Mb, int Nb) {
    __shared__ __align__(16) unsigned short As[2][128 * 64];
    __shared__ __align__(16) unsigned short Bs[2][128 * 64];
    const int tid  = threadIdx.x;
    const int w    = tid >> 6;
    const int lane = tid & 63;
    const int wm   = w >> 1, wn = w & 1;
    const int l15  = lane & 15, h4 = lane >> 4;

    // T1: bijective XCD swizzle (m204)
    const int nwg  = Mb * Nb;
    const int orig = blockIdx.x;
    const int qq   = nwg >> 3, rr8 = nwg & 7;
    const int xcd  = orig & 7, loc = orig >> 3;
    const int wgid = (xcd < rr8 ? xcd * (qq + 1) : rr8 * (qq + 1) + (xcd - rr8) * qq) + loc;
    const int nblk = wgid % Nb, mblk = wgid / Nb;
    const int m0 = mblk << 7, n0 = nblk << 7;

    // staging sources: thread t covers row g*32 + (t>>3), chunk (t&7);
    // T2 inverse swizzle on the global chunk ((t&7) ^ (row&7))
    const int r0 = tid >> 3;                       // 0..31
    const int cs = (((tid & 7) ^ (r0 & 7)) << 3);  // elem offset in row
    const unsigned short* ap[4];
    const unsigned short* bp[4];
    #pragma unroll
    for (int g = 0; g < 4; ++g) {
        ap[g] = A + (size_t)min(m0 + g * 32 + r0, M - 1) * K + cs;
        bp[g] = B + (size_t)(n0 + g * 32 + r0) * K + cs;
    }

#define GLL(src, dst) __builtin_amdgcn_global_load_lds((const AS1 void*)(src), (AS3 void*)(dst), 16, 0, 0)
#define STAGE_TILE(t, buf)                                                  \
    {                                                                       \
        const int koff_ = (t) << 6;                                         \
        _Pragma("unroll")                                                   \
        for (int g = 0; g < 4; ++g) {                                       \
            GLL(ap[g] + koff_, &As[buf][(g * 256 + tid) * 8]);              \
            GLL(bp[g] + koff_, &Bs[buf][(g * 256 + tid) * 8]);              \
        }                                                                   \
    }

    f32x4 acc[4][4] = {};

    STAGE_TILE(0, 0);
    STAGE_TILE(1, 1);
    asm volatile("s_waitcnt vmcnt(8)" ::: "memory");   // tile 0 landed
    __builtin_amdgcn_s_barrier();

    const int NT = K >> 6;
    for (int t = 0; t < NT; ++t) {
        const int buf = t & 1;
        bf16x8 af[2][4], bf[2][4];
        #pragma unroll
        for (int kb = 0; kb < 2; ++kb) {
            #pragma unroll
            for (int mf = 0; mf < 4; ++mf) {
                int row = wm * 64 + mf * 16 + l15;
                int ch  = (kb * 4 + h4) ^ (row & 7);
                af[kb][mf] = *(const bf16x8*)&As[buf][row * 64 + ch * 8];
            }
            #pragma unroll
            for (int nf = 0; nf < 4; ++nf) {
                int row = wn * 64 + nf * 16 + l15;
                int ch  = (kb * 4 + h4) ^ (row & 7);
                bf[kb][nf] = *(const bf16x8*)&Bs[buf][row * 64 + ch * 8];
            }
        }
        asm volatile("s_waitcnt lgkmcnt(0)" ::: "memory");
        __builtin_amdgcn_sched_barrier(0);
        __builtin_amdgcn_s_barrier();            // all waves done reading buf
        if (t + 2 < NT) STAGE_TILE(t + 2, buf);  // re-stage freed buffer

        __builtin_amdgcn_s_setprio(1);
        #pragma unroll
        for (int kb = 0; kb < 2; ++kb)
            #pragma unroll
            for (int mf = 0; mf < 4; ++mf)
                #pragma unroll
                for (int nf = 0; nf < 4; ++nf)
                    acc[mf][nf] = __builtin_amdgcn_mfma_f32_16x16x32_bf16(
                        af[kb][mf], bf[kb][nf], acc[mf][nf], 0, 0, 0);
        __builtin_amdgcn_s_setprio(0);

        if (t + 2 < NT)
            asm volatile("s_waitcnt vmcnt(8)" ::: "memory");   // tile t+1 landed
        else if (t + 1 < NT)
            asm volatile("s_waitcnt vmcnt(0)" ::: "memory");   // last drain
        __builtin_amdgcn_s_barrier();
    }
#undef STAGE_TILE
#undef GLL

    // ---- epilogue: per-wave 16KB LDS scratch -> coalesced stores ----
    __builtin_amdgcn_s_barrier();
    float* scr = (float*)As + (w << 12);     // 4096 f32 per wave (64KB total)
    const int rowbase = m0 + wm * 64;
    const int colbase = n0 + wn * 64;
    #pragma unroll
    for (int mf = 0; mf < 4; ++mf)
        #pragma unroll
        for (int nf = 0; nf < 4; ++nf)
            #pragma unroll
            for (int r = 0; r < 4; ++r) {
                int row = mf * 16 + (h4 << 2) + r;
                int col = nf * 16 + l15;
                float v = acc[mf][nf][r];
                int gcol = colbase + col;
                if (ADD_BIAS) v += bias[gcol];
                if (SCALE_Q && gcol < DIMC) v *= 0.125f;
                scr[(row << 6) + (col ^ ((row & 7) << 3))] = v;
            }
    if (OUT_BF16) {
        const int rr = lane >> 3, c8 = (lane & 7) << 3;
        #pragma unroll
        for (int k8 = 0; k8 < 8; ++k8) {
            int row = k8 * 8 + rr;
            int p = (row << 6) + (c8 ^ ((row & 7) << 3));
            f32x4 v0 = *(const f32x4*)&scr[p];
            f32x4 v1 = *(const f32x4*)&scr[p + 4];
            int grow = rowbase + row;
            if (grow < M) {
                u16x8 o;
                o[0] = f2bf(v0[0]); o[1] = f2bf(v0[1]); o[2] = f2bf(v0[2]); o[3] = f2bf(v0[3]);
                o[4] = f2bf(v1[0]); o[5] = f2bf(v1[1]); o[6] = f2bf(v1[2]); o[7] = f2bf(v1[3]);
                *(u16x8*)((unsigned short*)Cv + (size_t)grow * N + colbase + c8) = o;
            }
        }
    } else {
        const int rr = lane >> 4, c4 = (lane & 15) << 2;
        #pragma unroll
        for (int k4 = 0; k4 < 16; ++k4) {
            int row = k4 * 4 + rr;
            f32x4 v = *(const f32x4*)&scr[(row << 6) + (c4 ^ ((row & 7) << 3))];
            int grow = rowbase + row;
            if (grow < M)
                *(f32x4*)((float*)Cv + (size_t)grow * N + colbase + c4) = v;
        }
    }
}

// ---------------------------------------------------------------------------
// MFMA flash attention v2 (unchanged from R4/R5/R6)
// ---------------------------------------------------------------------------
__global__ __launch_bounds__(256)
void attn_mfma2(const unsigned short* __restrict__ qkv,
                const unsigned short* __restrict__ vtg,
                const unsigned short* __restrict__ biasF,
                unsigned short* __restrict__ att) {
    __shared__ __align__(16) unsigned short Ks[64 * 64];
    __shared__ __align__(16) unsigned short Vs[64 * 64];
    __shared__ __align__(16) unsigned short Ps[128 * 64];

    const int b    = blockIdx.z;
    const int h    = blockIdx.y;
    const int i0b  = blockIdx.x;
    const int i0   = i0b << 7;
    const int tid  = threadIdx.x;
    const int w    = tid >> 6;
    const int lane = tid & 63;
    const int l15  = lane & 15;
    const int h4   = lane >> 4;
    const int sw   = (l15 & 7) << 3;

    bf16x8 qf[2][2];
    #pragma unroll
    for (int qi = 0; qi < 2; ++qi) {
        int qrow = min(i0 + w * 32 + qi * 16 + l15, NTOK - 1);
        const unsigned short* qp = qkv + (size_t)(b * NTOK + qrow) * 2304 + h * HDIM + h4 * 8;
        qf[qi][0] = *(const bf16x8*)qp;
        qf[qi][1] = *(const bf16x8*)(qp + 32);
    }

    const int grow   = lane >> 3;
    const int gchunk = (lane & 7) ^ grow;
    const unsigned short* kls = qkv + (size_t)b * NTOK * 2304 + DIMC + h * HDIM + gchunk * 8;
    const unsigned short* vls = vtg + (size_t)((b * HEADS + h) * HDIM) * 640 + gchunk * 8;
    const unsigned short* bias_p = biasF + ((size_t)(((h * NQB + i0b) * NCH) * 4 + w) * 64 + lane) * 32;

    float l[2] = {0.f, 0.f};
    f32x4 o[2][4] = {};

    for (int c = 0; c < NCH; ++c) {
        __syncthreads();
        #pragma unroll
        for (int t = 0; t < 2; ++t) {
            const int rbase = w * 16 + t * 8;
            const int rloc  = rbase + grow;
            const int ktok  = min(c * 64 + rloc, NTOK - 1);
            __builtin_amdgcn_global_load_lds((const AS1 void*)(kls + (size_t)ktok * 2304),
                                             (AS3 void*)(Ks + rbase * 64), 16, 0, 0);
            __builtin_amdgcn_global_load_lds((const AS1 void*)(vls + rloc * 640 + c * 64),
                                             (AS3 void*)(Vs + rbase * 64), 16, 0, 0);
        }
        u16x8 br[4];
        {
            const unsigned short* bp = bias_p + c * 8192;
            #pragma unroll
            for (int t = 0; t < 4; ++t) br[t] = *(const u16x8*)(bp + t * 8);
        }
        __syncthreads();

        __builtin_amdgcn_s_setprio(1);
        f32x4 sacc[4][2] = {};
        #pragma unroll
        for (int kb = 0; kb < 2; ++kb) {
            #pragma unroll
            for (int bb = 0; bb < 4; ++bb) {
                bf16x8 kf = *(const bf16x8*)&Ks[(bb * 16 + l15) * 64 + ((kb * 32 + h4 * 8) ^ sw)];
                sacc[bb][0] = __builtin_amdgcn_mfma_f32_16x16x32_bf16(kf, qf[0][kb], sacc[bb][0], 0, 0, 0);
                sacc[bb][1] = __builtin_amdgcn_mfma_f32_16x16x32_bf16(kf, qf[1][kb], sacc[bb][1], 0, 0, 0);
            }
        }
        __builtin_amdgcn_s_setprio(0);

        #pragma unroll
        for (int qi = 0; qi < 2; ++qi) {
            float rs = 0.f;
            #pragma unroll
            for (int bb = 0; bb < 4; ++bb) {
                const u16x8 bv = br[qi * 2 + (bb >> 1)];
                const int   e0 = (bb & 1) * 4;
                float p0 = __expf(sacc[bb][qi][0] + bf2f((unsigned short)bv[e0 + 0]));
                float p1 = __expf(sacc[bb][qi][1] + bf2f((unsigned short)bv[e0 + 1]));
                float p2 = __expf(sacc[bb][qi][2] + bf2f((unsigned short)bv[e0 + 2]));
                float p3 = __expf(sacc[bb][qi][3] + bf2f((unsigned short)bv[e0 + 3]));
                rs += (p0 + p1) + (p2 + p3);
                ushort4 pw;
                pw.x = f2bf(p0); pw.y = f2bf(p1); pw.z = f2bf(p2); pw.w = f2bf(p3);
                *(ushort4*)&Ps[(w * 32 + qi * 16 + l15) * 64 + ((bb * 16 + h4 * 4) ^ sw)] = pw;
            }
            rs += __shfl_xor(rs, 16);
            rs += __shfl_xor(rs, 32);
            l[qi] += rs;
        }

        __builtin_amdgcn_s_setprio(1);
        #pragma unroll
        for (int kb = 0; kb < 2; ++kb) {
            bf16x8 vf[4];
            #pragma unroll
            for (int nb = 0; nb < 4; ++nb)
                vf[nb] = *(const bf16x8*)&Vs[(nb * 16 + l15) * 64 + ((kb * 32 + h4 * 8) ^ sw)];
            #pragma unroll
            for (int qi = 0; qi < 2; ++qi) {
                bf16x8 pf = *(const bf16x8*)&Ps[(w * 32 + qi * 16 + l15) * 64 + ((kb * 32 + h4 * 8) ^ sw)];
                #pragma unroll
                for (int nb = 0; nb < 4; ++nb)
                    o[qi][nb] = __builtin_amdgcn_mfma_f32_16x16x32_bf16(pf, vf[nb], o[qi][nb], 0, 0, 0);
            }
        }
        __builtin_amdgcn_s_setprio(0);
    }

    #pragma unroll
    for (int qi = 0; qi < 2; ++qi) {
        #pragma unroll
        for (int r = 0; r < 4; ++r) {
            float linv = 1.0f / __shfl(l[qi], (h4 << 2) + r);
            int qrow = i0 + w * 32 + qi * 16 + (h4 << 2) + r;
            if (qrow < NTOK) {
                #pragma unroll
                for (int nb = 0; nb < 4; ++nb)
                    att[(size_t)(b * NTOK + qrow) * DIMC + h * HDIM + nb * 16 + l15] =
                        f2bf(o[qi][nb][r] * linv);
            }
        }
    }
}

// ---------------------------------------------------------------------------
// Launch
// ---------------------------------------------------------------------------
extern "C" void kernel_launch(void* const* d_in, const int* in_sizes, int n_in,
                              void* d_out, int out_size, void* d_ws, size_t ws_size,
                              hipStream_t stream) {
    const float* x      = (const float*)d_in[0];
    const float* qkv_w  = (const float*)d_in[1];
    const float* proj_w = (const float*)d_in[2];
    const float* proj_b = (const float*)d_in[3];
    const float* beta1  = (const float*)d_in[4];
    const float* beta2  = (const float*)d_in[5];
    const float* beta3  = (const float*)d_in[6];
    float* out = (float*)d_out;

    unsigned short* qkvbf = (unsigned short*)d_ws;                 // 18464*2304
    unsigned short* attbf = qkvbf + (size_t)MROWS * 2304;          // 18464*768
    unsigned short* xbf   = attbf + (size_t)MROWS * DIMC;          // 18464*768
    unsigned short* wqkv  = xbf   + (size_t)MROWS * DIMC;          // 2304*768
    unsigned short* wproj = wqkv  + (size_t)2304 * DIMC;           // 768*768
    unsigned short* vtg   = wproj + (size_t)DIMC * DIMC;           // 384*64*640
    unsigned short* biasF = vtg   + (size_t)BATCH * HEADS * HDIM * 640; // 4,915,200

    f32_to_bf16_kernel<<<2048, 256, 0, stream>>>(x, xbf, MROWS * DIMC / 4);
    f32_to_bf16_kernel<<<1024, 256, 0, stream>>>(qkv_w, wqkv, 2304 * DIMC / 4);
    f32_to_bf16_kernel<<<512, 256, 0, stream>>>(proj_w, wproj, DIMC * DIMC / 4);

    build_biasF_kernel<<<(HEADS * NQB * NCH * 4 * 64 * 32 + 255) / 256, 256, 0, stream>>>(
        beta1, beta2, beta3, biasF);

    {   // QKV: (18464 x 768) @ (2304 x 768)^T -> bf16, q-cols scaled by 1/8
        const int Mb = (MROWS + 127) / 128, Nb = (3 * DIMC) / 128;
        gemm_128<false, true, true><<<Mb * Nb, 256, 0, stream>>>(
            xbf, wqkv, nullptr, qkvbf, MROWS, 3 * DIMC, DIMC, Mb, Nb);
    }
    {   // V transpose
        dim3 g(NCH, HEADS, BATCH);
        vt_build_kernel<<<g, 256, 0, stream>>>(qkvbf, vtg);
    }
    {   // fused MFMA attention
        dim3 g(NQB, HEADS, BATCH);
        attn_mfma2<<<g, 256, 0, stream>>>(qkvbf, vtg, biasF, attbf);
    }
    {   // proj: (18464 x 768) @ (768 x 768)^T + bias -> fp32 out
        const int Mb = (MROWS + 127) / 128, Nb = DIMC / 128;
        gemm_128<true, false, false><<<Mb * Nb, 256, 0, stream>>>(
            attbf, wproj, proj_b, out, MROWS, DIMC, DIMC, Mb, Nb);
    }
}

// Round 9
// 329.203 us; speedup vs baseline: 1.0786x; 1.0786x over previous
//
#include <hip/hip_runtime.h>
#include <math.h>

#define DIMC  768
#define HEADS 12
#define NTOK  577
#define NPAT  576
#define NRELS 2209
#define BATCH 32
#define HDIM  64
#define MROWS (BATCH * NTOK)   // 18464
#define NQB   5                // q-blocks of 128 (640 padded rows)
#define NCH   10               // kv chunks of 64 (640 padded cols)
#define LOG2E 1.4426950408889634f
#define QSC   (0.125f * LOG2E) // folded q-scale (1/sqrt(64) * log2e)

#define AS1 __attribute__((address_space(1)))
#define AS3 __attribute__((address_space(3)))

typedef __attribute__((ext_vector_type(8))) short bf16x8;
typedef __attribute__((ext_vector_type(4))) float f32x4;
typedef __attribute__((ext_vector_type(8))) unsigned short u16x8;

__device__ __forceinline__ unsigned short f2bf(float f) {
    unsigned int u = __float_as_uint(f);
    return (unsigned short)((u + 0x7FFFu + ((u >> 16) & 1u)) >> 16);
}
__device__ __forceinline__ float bf2f(unsigned short h) {
    return __uint_as_float(((unsigned int)h) << 16);
}
__device__ __forceinline__ unsigned int cvt_pk_bf16(float lo, float hi) {
    unsigned int r;
    asm("v_cvt_pk_bf16_f32 %0, %1, %2" : "=v"(r) : "v"(lo), "v"(hi));
    return r;
}

// ---------------------------------------------------------------------------
// fused fp32 -> bf16 convert for 3 buffers (one launch)
// ---------------------------------------------------------------------------
__global__ __launch_bounds__(256)
void cvt3_kernel(const float* __restrict__ s1, unsigned short* __restrict__ d1, int n1,
                 const float* __restrict__ s2, unsigned short* __restrict__ d2, int n2,
                 const float* __restrict__ s3, unsigned short* __restrict__ d3, int n3) {
    const int total = n1 + n2 + n3;
    for (int i = blockIdx.x * 256 + threadIdx.x; i < total; i += gridDim.x * 256) {
        const float* s; unsigned short* d; int k;
        if (i < n1)            { s = s1; d = d1; k = i; }
        else if (i < n1 + n2)  { s = s2; d = d2; k = i - n1; }
        else                   { s = s3; d = d3; k = i - n1 - n2; }
        float4 v = reinterpret_cast<const float4*>(s)[k];
        ushort4 r;
        r.x = f2bf(v.x); r.y = f2bf(v.y); r.z = f2bf(v.z); r.w = f2bf(v.w);
        reinterpret_cast<ushort4*>(d)[k] = r;
    }
}

// ---------------------------------------------------------------------------
// Bias panel in MFMA-fragment order, PRE-SCALED by log2e (exp2 path).
// ---------------------------------------------------------------------------
__global__ __launch_bounds__(256)
void build_biasF_kernel(const float* __restrict__ beta1,
                        const float* __restrict__ beta2,
                        const float* __restrict__ beta3,
                        unsigned short* __restrict__ biasF) {
    int idx = blockIdx.x * 256 + threadIdx.x;
    const int total = HEADS * NQB * NCH * 4 * 64 * 32;
    if (idx >= total) return;
    int r    = idx & 3;
    int bb   = (idx >> 2) & 3;
    int qi   = (idx >> 4) & 1;
    int lane = (idx >> 5) & 63;
    int wv   = (idx >> 11) & 3;
    int u    = idx >> 13;
    int c    = u % NCH;
    int i0b  = (u / NCH) % NQB;
    int h    = u / (NCH * NQB);
    int q = i0b * 128 + wv * 32 + qi * 16 + (lane & 15);
    int j = c * 64 + bb * 16 + ((lane >> 4) << 2) + r;
    float v;
    if (q >= NTOK || j >= NTOK) {
        v = -1e30f;
    } else if (q == NPAT) {
        v = beta1[h * NTOK + j];
    } else if (j == 0) {
        v = beta2[h * NPAT + q];
    } else {
        int p   = j - 1;
        int qi_ = q / 24, qj = q - qi_ * 24;
        int ri  = p / 24, ci = p - ri * 24;
        v = beta3[h * NRELS + (ri - qi_ + 23) * 47 + (ci - qj + 23)];
    }
    biasF[idx] = f2bf(v * LOG2E);
}

// ---------------------------------------------------------------------------
// V transpose (unchanged)
// ---------------------------------------------------------------------------
__global__ __launch_bounds__(256)
void vt_build_kernel(const unsigned short* __restrict__ qkv,
                     unsigned short* __restrict__ vtg) {
    __shared__ unsigned short T[64][72];
    const int c = blockIdx.x, h = blockIdx.y, b = blockIdx.z;
    const int tid = threadIdx.x;
    {
        int tok   = tid >> 2;
        int dq    = (tid & 3) << 4;
        int token = min(c * 64 + tok, NTOK - 1);
        const unsigned short* src = qkv + (size_t)(b * NTOK + token) * 2304 + 2 * DIMC + h * HDIM + dq;
        u16x8 a0 = *(const u16x8*)src;
        u16x8 a1 = *(const u16x8*)(src + 8);
        #pragma unroll
        for (int e = 0; e < 8; ++e) {
            T[dq + e][tok]     = (unsigned short)a0[e];
            T[dq + 8 + e][tok] = (unsigned short)a1[e];
        }
    }
    __syncthreads();
    {
        int d  = tid >> 2;
        int tq = (tid & 3) << 4;
        u16x8 r0 = *(const u16x8*)&T[d][tq];
        u16x8 r1 = *(const u16x8*)&T[d][tq + 8];
        unsigned short* dst = vtg + ((size_t)((b * HEADS + h) * HDIM) + d) * 640 + c * 64 + tq;
        *(u16x8*)dst       = r0;
        *(u16x8*)(dst + 8) = r1;
    }
}

// ---------------------------------------------------------------------------
// 128x128x(K) bf16 MFMA GEMM (unchanged from R7; SCALE_Q now QSC=log2e/8)
// ---------------------------------------------------------------------------
template<bool ADD_BIAS, bool OUT_BF16, bool SCALE_Q>
__global__ __launch_bounds__(256, 2)
void gemm_128(const unsigned short* __restrict__ A,
              const unsigned short* __restrict__ B,
              const float* __restrict__ bias,
              void* __restrict__ Cv,
              int M, int N, int K, int Mb, int Nb) {
    __shared__ __align__(16) unsigned short As[2][128 * 64];
    __shared__ __align__(16) unsigned short Bs[2][128 * 64];
    const int tid  = threadIdx.x;
    const int w    = tid >> 6;
    const int lane = tid & 63;
    const int wm   = w >> 1, wn = w & 1;
    const int l15  = lane & 15, h4 = lane >> 4;

    const int nwg  = Mb * Nb;
    const int orig = blockIdx.x;
    const int qq   = nwg >> 3, rr8 = nwg & 7;
    const int xcd  = orig & 7, loc = orig >> 3;
    const int wgid = (xcd < rr8 ? xcd * (qq + 1) : rr8 * (qq + 1) + (xcd - rr8) * qq) + loc;
    const int nblk = wgid % Nb, mblk = wgid / Nb;
    const int m0 = mblk << 7, n0 = nblk << 7;

    const int r0 = tid >> 3;
    const int cs = (((tid & 7) ^ (r0 & 7)) << 3);
    const unsigned short* ap[4];
    const unsigned short* bp[4];
    #pragma unroll
    for (int g = 0; g < 4; ++g) {
        ap[g] = A + (size_t)min(m0 + g * 32 + r0, M - 1) * K + cs;
        bp[g] = B + (size_t)(n0 + g * 32 + r0) * K + cs;
    }

#define GLL(src, dst) __builtin_amdgcn_global_load_lds((const AS1 void*)(src), (AS3 void*)(dst), 16, 0, 0)
#define STAGE_TILE(t, buf)                                                  \
    {                                                                       \
        const int koff_ = (t) << 6;                                         \
        _Pragma("unroll")                                                   \
        for (int g = 0; g < 4; ++g) {                                       \
            GLL(ap[g] + koff_, &As[buf][(g * 256 + tid) * 8]);              \
            GLL(bp[g] + koff_, &Bs[buf][(g * 256 + tid) * 8]);              \
        }                                                                   \
    }

    f32x4 acc[4][4] = {};

    STAGE_TILE(0, 0);
    STAGE_TILE(1, 1);
    asm volatile("s_waitcnt vmcnt(8)" ::: "memory");
    __builtin_amdgcn_s_barrier();

    const int NT = K >> 6;
    for (int t = 0; t < NT; ++t) {
        const int buf = t & 1;
        bf16x8 af[2][4], bf[2][4];
        #pragma unroll
        for (int kb = 0; kb < 2; ++kb) {
            #pragma unroll
            for (int mf = 0; mf < 4; ++mf) {
                int row = wm * 64 + mf * 16 + l15;
                int ch  = (kb * 4 + h4) ^ (row & 7);
                af[kb][mf] = *(const bf16x8*)&As[buf][row * 64 + ch * 8];
            }
            #pragma unroll
            for (int nf = 0; nf < 4; ++nf) {
                int row = wn * 64 + nf * 16 + l15;
                int ch  = (kb * 4 + h4) ^ (row & 7);
                bf[kb][nf] = *(const bf16x8*)&Bs[buf][row * 64 + ch * 8];
            }
        }
        asm volatile("s_waitcnt lgkmcnt(0)" ::: "memory");
        __builtin_amdgcn_sched_barrier(0);
        __builtin_amdgcn_s_barrier();
        if (t + 2 < NT) STAGE_TILE(t + 2, buf);

        __builtin_amdgcn_s_setprio(1);
        #pragma unroll
        for (int kb = 0; kb < 2; ++kb)
            #pragma unroll
            for (int mf = 0; mf < 4; ++mf)
                #pragma unroll
                for (int nf = 0; nf < 4; ++nf)
                    acc[mf][nf] = __builtin_amdgcn_mfma_f32_16x16x32_bf16(
                        af[kb][mf], bf[kb][nf], acc[mf][nf], 0, 0, 0);
        __builtin_amdgcn_s_setprio(0);

        if (t + 2 < NT)
            asm volatile("s_waitcnt vmcnt(8)" ::: "memory");
        else if (t + 1 < NT)
            asm volatile("s_waitcnt vmcnt(0)" ::: "memory");
        __builtin_amdgcn_s_barrier();
    }
#undef STAGE_TILE
#undef GLL

    __builtin_amdgcn_s_barrier();
    float* scr = (float*)As + (w << 12);
    const int rowbase = m0 + wm * 64;
    const int colbase = n0 + wn * 64;
    #pragma unroll
    for (int mf = 0; mf < 4; ++mf)
        #pragma unroll
        for (int nf = 0; nf < 4; ++nf)
            #pragma unroll
            for (int r = 0; r < 4; ++r) {
                int row = mf * 16 + (h4 << 2) + r;
                int col = nf * 16 + l15;
                float v = acc[mf][nf][r];
                int gcol = colbase + col;
                if (ADD_BIAS) v += bias[gcol];
                if (SCALE_Q && gcol < DIMC) v *= QSC;
                scr[(row << 6) + (col ^ ((row & 7) << 3))] = v;
            }
    if (OUT_BF16) {
        const int rr = lane >> 3, c8 = (lane & 7) << 3;
        #pragma unroll
        for (int k8 = 0; k8 < 8; ++k8) {
            int row = k8 * 8 + rr;
            int p = (row << 6) + (c8 ^ ((row & 7) << 3));
            f32x4 v0 = *(const f32x4*)&scr[p];
            f32x4 v1 = *(const f32x4*)&scr[p + 4];
            int grow = rowbase + row;
            if (grow < M) {
                u16x8 o;
                o[0] = f2bf(v0[0]); o[1] = f2bf(v0[1]); o[2] = f2bf(v0[2]); o[3] = f2bf(v0[3]);
                o[4] = f2bf(v1[0]); o[5] = f2bf(v1[1]); o[6] = f2bf(v1[2]); o[7] = f2bf(v1[3]);
                *(u16x8*)((unsigned short*)Cv + (size_t)grow * N + colbase + c8) = o;
            }
        }
    } else {
        const int rr = lane >> 4, c4 = (lane & 15) << 2;
        #pragma unroll
        for (int k4 = 0; k4 < 16; ++k4) {
            int row = k4 * 4 + rr;
            f32x4 v = *(const f32x4*)&scr[(row << 6) + (c4 ^ ((row & 7) << 3))];
            int grow = rowbase + row;
            if (grow < M)
                *(f32x4*)((float*)Cv + (size_t)grow * N + colbase + c4) = v;
        }
    }
}

// ---------------------------------------------------------------------------
// MFMA flash attention v3: XCD-grouped grid (5 i0b-blocks of one (b,h) land
// adjacent on the same XCD -> K/V L2 reuse), exp2 path (log2e pre-folded into
// Q and bias), v_cvt_pk_bf16_f32 P-pack. Structure otherwise as R4-R7.
// Grid: 1D 1920. orig -> xcd = orig&7, j = orig>>3; unit = xcd + 8*(j/5);
// i0b = j%5; h = unit%12, b = unit/12.
// ---------------------------------------------------------------------------
__global__ __launch_bounds__(256)
void attn_mfma3(const unsigned short* __restrict__ qkv,
                const unsigned short* __restrict__ vtg,
                const unsigned short* __restrict__ biasF,
                unsigned short* __restrict__ att) {
    __shared__ __align__(16) unsigned short Ks[64 * 64];
    __shared__ __align__(16) unsigned short Vs[64 * 64];
    __shared__ __align__(16) unsigned short Ps[128 * 64];

    const int orig = blockIdx.x;
    const int xcd  = orig & 7;
    const int jj   = orig >> 3;
    const int ul   = jj / 5;
    const int i0b  = jj - ul * 5;
    const int unit = xcd + (ul << 3);
    const int h    = unit % HEADS;
    const int b    = unit / HEADS;

    const int i0   = i0b << 7;
    const int tid  = threadIdx.x;
    const int w    = tid >> 6;
    const int lane = tid & 63;
    const int l15  = lane & 15;
    const int h4   = lane >> 4;
    const int sw   = (l15 & 7) << 3;

    bf16x8 qf[2][2];
    #pragma unroll
    for (int qi = 0; qi < 2; ++qi) {
        int qrow = min(i0 + w * 32 + qi * 16 + l15, NTOK - 1);
        const unsigned short* qp = qkv + (size_t)(b * NTOK + qrow) * 2304 + h * HDIM + h4 * 8;
        qf[qi][0] = *(const bf16x8*)qp;
        qf[qi][1] = *(const bf16x8*)(qp + 32);
    }

    const int grow   = lane >> 3;
    const int gchunk = (lane & 7) ^ grow;
    const unsigned short* kls = qkv + (size_t)b * NTOK * 2304 + DIMC + h * HDIM + gchunk * 8;
    const unsigned short* vls = vtg + (size_t)((b * HEADS + h) * HDIM) * 640 + gchunk * 8;
    const unsigned short* bias_p = biasF + ((size_t)(((h * NQB + i0b) * NCH) * 4 + w) * 64 + lane) * 32;

    float l[2] = {0.f, 0.f};
    f32x4 o[2][4] = {};

    for (int c = 0; c < NCH; ++c) {
        __syncthreads();
        #pragma unroll
        for (int t = 0; t < 2; ++t) {
            const int rbase = w * 16 + t * 8;
            const int rloc  = rbase + grow;
            const int ktok  = min(c * 64 + rloc, NTOK - 1);
            __builtin_amdgcn_global_load_lds((const AS1 void*)(kls + (size_t)ktok * 2304),
                                             (AS3 void*)(Ks + rbase * 64), 16, 0, 0);
            __builtin_amdgcn_global_load_lds((const AS1 void*)(vls + rloc * 640 + c * 64),
                                             (AS3 void*)(Vs + rbase * 64), 16, 0, 0);
        }
        u16x8 br[4];
        {
            const unsigned short* bp = bias_p + c * 8192;
            #pragma unroll
            for (int t = 0; t < 4; ++t) br[t] = *(const u16x8*)(bp + t * 8);
        }
        __syncthreads();

        __builtin_amdgcn_s_setprio(1);
        f32x4 sacc[4][2] = {};
        #pragma unroll
        for (int kb = 0; kb < 2; ++kb) {
            #pragma unroll
            for (int bb = 0; bb < 4; ++bb) {
                bf16x8 kf = *(const bf16x8*)&Ks[(bb * 16 + l15) * 64 + ((kb * 32 + h4 * 8) ^ sw)];
                sacc[bb][0] = __builtin_amdgcn_mfma_f32_16x16x32_bf16(kf, qf[0][kb], sacc[bb][0], 0, 0, 0);
                sacc[bb][1] = __builtin_amdgcn_mfma_f32_16x16x32_bf16(kf, qf[1][kb], sacc[bb][1], 0, 0, 0);
            }
        }
        __builtin_amdgcn_s_setprio(0);

        #pragma unroll
        for (int qi = 0; qi < 2; ++qi) {
            float rs = 0.f;
            #pragma unroll
            for (int bb = 0; bb < 4; ++bb) {
                const u16x8 bv = br[qi * 2 + (bb >> 1)];
                const int   e0 = (bb & 1) * 4;
                float p0 = __builtin_amdgcn_exp2f(sacc[bb][qi][0] + bf2f((unsigned short)bv[e0 + 0]));
                float p1 = __builtin_amdgcn_exp2f(sacc[bb][qi][1] + bf2f((unsigned short)bv[e0 + 1]));
                float p2 = __builtin_amdgcn_exp2f(sacc[bb][qi][2] + bf2f((unsigned short)bv[e0 + 2]));
                float p3 = __builtin_amdgcn_exp2f(sacc[bb][qi][3] + bf2f((unsigned short)bv[e0 + 3]));
                rs += (p0 + p1) + (p2 + p3);
                unsigned int u0 = cvt_pk_bf16(p0, p1);
                unsigned int u1 = cvt_pk_bf16(p2, p3);
                *(uint2*)&Ps[(w * 32 + qi * 16 + l15) * 64 + ((bb * 16 + h4 * 4) ^ sw)] =
                    make_uint2(u0, u1);
            }
            rs += __shfl_xor(rs, 16);
            rs += __shfl_xor(rs, 32);
            l[qi] += rs;
        }

        __builtin_amdgcn_s_setprio(1);
        #pragma unroll
        for (int kb = 0; kb < 2; ++kb) {
            bf16x8 vf[4];
            #pragma unroll
            for (int nb = 0; nb < 4; ++nb)
                vf[nb] = *(const bf16x8*)&Vs[(nb * 16 + l15) * 64 + ((kb * 32 + h4 * 8) ^ sw)];
            #pragma unroll
            for (int qi = 0; qi < 2; ++qi) {
                bf16x8 pf = *(const bf16x8*)&Ps[(w * 32 + qi * 16 + l15) * 64 + ((kb * 32 + h4 * 8) ^ sw)];
                #pragma unroll
                for (int nb = 0; nb < 4; ++nb)
                    o[qi][nb] = __builtin_amdgcn_mfma_f32_16x16x32_bf16(pf, vf[nb], o[qi][nb], 0, 0, 0);
            }
        }
        __builtin_amdgcn_s_setprio(0);
    }

    #pragma unroll
    for (int qi = 0; qi < 2; ++qi) {
        #pragma unroll
        for (int r = 0; r < 4; ++r) {
            float linv = 1.0f / __shfl(l[qi], (h4 << 2) + r);
            int qrow = i0 + w * 32 + qi * 16 + (h4 << 2) + r;
            if (qrow < NTOK) {
                #pragma unroll
                for (int nb = 0; nb < 4; ++nb)
                    att[(size_t)(b * NTOK + qrow) * DIMC + h * HDIM + nb * 16 + l15] =
                        f2bf(o[qi][nb][r] * linv);
            }
        }
    }
}

// ---------------------------------------------------------------------------
// Launch
// ---------------------------------------------------------------------------
extern "C" void kernel_launch(void* const* d_in, const int* in_sizes, int n_in,
                              void* d_out, int out_size, void* d_ws, size_t ws_size,
                              hipStream_t stream) {
    const float* x      = (const float*)d_in[0];
    const float* qkv_w  = (const float*)d_in[1];
    const float* proj_w = (const float*)d_in[2];
    const float* proj_b = (const float*)d_in[3];
    const float* beta1  = (const float*)d_in[4];
    const float* beta2  = (const float*)d_in[5];
    const float* beta3  = (const float*)d_in[6];
    float* out = (float*)d_out;

    unsigned short* qkvbf = (unsigned short*)d_ws;                 // 18464*2304
    unsigned short* attbf = qkvbf + (size_t)MROWS * 2304;          // 18464*768
    unsigned short* xbf   = attbf + (size_t)MROWS * DIMC;          // 18464*768
    unsigned short* wqkv  = xbf   + (size_t)MROWS * DIMC;          // 2304*768
    unsigned short* wproj = wqkv  + (size_t)2304 * DIMC;           // 768*768
    unsigned short* vtg   = wproj + (size_t)DIMC * DIMC;           // 384*64*640
    unsigned short* biasF = vtg   + (size_t)BATCH * HEADS * HDIM * 640; // 4,915,200

    cvt3_kernel<<<2048, 256, 0, stream>>>(x, xbf, MROWS * DIMC / 4,
                                          qkv_w, wqkv, 2304 * DIMC / 4,
                                          proj_w, wproj, DIMC * DIMC / 4);

    build_biasF_kernel<<<(HEADS * NQB * NCH * 4 * 64 * 32 + 255) / 256, 256, 0, stream>>>(
        beta1, beta2, beta3, biasF);

    {   // QKV: (18464 x 768) @ (2304 x 768)^T -> bf16, q-cols scaled by log2e/8
        const int Mb = (MROWS + 127) / 128, Nb = (3 * DIMC) / 128;
        gemm_128<false, true, true><<<Mb * Nb, 256, 0, stream>>>(
            xbf, wqkv, nullptr, qkvbf, MROWS, 3 * DIMC, DIMC, Mb, Nb);
    }
    {   // V transpose
        dim3 g(NCH, HEADS, BATCH);
        vt_build_kernel<<<g, 256, 0, stream>>>(qkvbf, vtg);
    }
    {   // fused MFMA attention (XCD-grouped 1D grid)
        attn_mfma3<<<NQB * HEADS * BATCH, 256, 0, stream>>>(qkvbf, vtg, biasF, attbf);
    }
    {   // proj: (18464 x 768) @ (768 x 768)^T + bias -> fp32 out
        const int Mb = (MROWS + 127) / 128, Nb = DIMC / 128;
        gemm_128<true, false, false><<<Mb * Nb, 256, 0, stream>>>(
            attbf, wproj, proj_b, out, MROWS, DIMC, DIMC, Mb, Nb);
    }
}